// Round 20
// baseline (140.704 us; speedup 1.0000x reference)
//
#include <hip/hip_runtime.h>
#include <math.h>

// ---------------------------------------------------------------------------
// 2-layer GCN (PyG GCNConv) on MI355X — tiled-partition CSR + MLP-deep gather.
// Fused hist+gemm launch; 1-launch scan (consumers add bsum-prefix locally);
// bucketCSR quarter-ordered (4 bins) + pass-4 in-place g1 scaling. 6 launches.
// out[i] = logsoftmax( dinv[i]*(g2[i] + sum_{e:dst=i} g2[src_e]) + b2 )
// g2 = dinv*( relu( dinv*(g1[i]+sum g1[src]) + b1 ) @ W2 ), g1 = (x@W1)*dinv
// ---------------------------------------------------------------------------

#define F_IN   128
#define F_HID  32
#define F_OUT  7
#define TILE   8192
#define BSH    8              // 256 nodes per bucket
#define BNODES 256
#define HSZ    512            // LDS histogram capacity (>= NB = 391)
#define PCAP   10240          // LDS sorted-output capacity (avg bucket 8184)

typedef __attribute__((ext_vector_type(8))) short bf16x8;
typedef __attribute__((ext_vector_type(4))) float f32x4;
typedef __attribute__((ext_vector_type(4))) int   i32x4;

__device__ __forceinline__ float bf2f(unsigned short u) {
    return __uint_as_float(((unsigned int)u) << 16);
}
__device__ __forceinline__ unsigned short f2bf(float f) {
    unsigned int u = __float_as_uint(f);
    u += 0x7FFF + ((u >> 16) & 1);   // round-to-nearest-even
    return (unsigned short)(u >> 16);
}
__device__ __forceinline__ unsigned int pack2(unsigned short lo, unsigned short hi) {
    return (unsigned int)lo | ((unsigned int)hi << 16);
}
#define NTL(p) __builtin_nontemporal_load(p)

// accumulate 8 bf16 (uint4) into 8 fp32
__device__ __forceinline__ void acc8(float* a, uint4 v) {
    a[0] += bf2f((unsigned short)v.x); a[1] += bf2f((unsigned short)(v.x >> 16));
    a[2] += bf2f((unsigned short)v.y); a[3] += bf2f((unsigned short)(v.y >> 16));
    a[4] += bf2f((unsigned short)v.z); a[5] += bf2f((unsigned short)(v.z >> 16));
    a[6] += bf2f((unsigned short)v.w); a[7] += bf2f((unsigned short)(v.w >> 16));
}

// Fused launch: blocks [0,NT) = per-tile dst histogram; blocks [NT,..) = GEMM1.
__global__ __launch_bounds__(512)
void k_histGemm(const int* __restrict__ dst, int E, int NB, int NT,
                int* __restrict__ counts,
                const float* __restrict__ x, const float* __restrict__ W1,
                unsigned short* __restrict__ g1b, int n) {
    int t = threadIdx.x;
    if (blockIdx.x < (unsigned)NT) {
        __shared__ int h[HSZ];
        int tile = blockIdx.x;
        for (int i = t; i < NB; i += 512) h[i] = 0;
        __syncthreads();
        int base = tile * TILE;
        int lim = base + TILE; if (lim > E) lim = E;
        int n4 = (lim - base) >> 2;
        const i32x4* d4 = (const i32x4*)(dst + base);
        for (int i = t; i < n4; i += 512) {
            i32x4 d = NTL(&d4[i]);
            atomicAdd(&h[d[0] >> BSH], 1);
            atomicAdd(&h[d[1] >> BSH], 1);
            atomicAdd(&h[d[2] >> BSH], 1);
            atomicAdd(&h[d[3] >> BSH], 1);
        }
        __syncthreads();
        for (int i = t; i < NB; i += 512) counts[tile * NB + i] = h[i];
        return;
    }
    // ---- GEMM1 tile (unscaled): g1u = bf16(x @ W1) ----
    int gb = blockIdx.x - NT;
    int wave = t >> 6;                    // 0..7
    int lane = t & 63;
    int row0 = (gb * 8 + wave) * 16;
    if (row0 >= n) return;                // n % 16 == 0
    bf16x8 bfr[2][4];
    #pragma unroll
    for (int nt = 0; nt < 2; ++nt)
        #pragma unroll
        for (int ks = 0; ks < 4; ++ks) {
            bf16x8 w;
            #pragma unroll
            for (int j = 0; j < 8; ++j) {
                int k = ks * 32 + ((lane >> 4) << 3) + j;
                w[j] = (short)f2bf(W1[k * F_HID + nt * 16 + (lane & 15)]);
            }
            bfr[nt][ks] = w;
        }
    int arow = row0 + (lane & 15);
    const float* xr = x + (size_t)arow * F_IN + ((lane >> 4) << 3);
    f32x4 acc0 = {0.f, 0.f, 0.f, 0.f};
    f32x4 acc1 = {0.f, 0.f, 0.f, 0.f};
    #pragma unroll
    for (int ks = 0; ks < 4; ++ks) {
        f32x4 lo = NTL((const f32x4*)(xr + ks * 32));
        f32x4 hi = NTL((const f32x4*)(xr + ks * 32 + 4));
        bf16x8 a;
        a[0] = (short)f2bf(lo[0]); a[1] = (short)f2bf(lo[1]);
        a[2] = (short)f2bf(lo[2]); a[3] = (short)f2bf(lo[3]);
        a[4] = (short)f2bf(hi[0]); a[5] = (short)f2bf(hi[1]);
        a[6] = (short)f2bf(hi[2]); a[7] = (short)f2bf(hi[3]);
        acc0 = __builtin_amdgcn_mfma_f32_16x16x32_bf16(a, bfr[0][ks], acc0, 0, 0, 0);
        acc1 = __builtin_amdgcn_mfma_f32_16x16x32_bf16(a, bfr[1][ks], acc1, 0, 0, 0);
    }
    int col = lane & 15;
    #pragma unroll
    for (int rr = 0; rr < 4; ++rr) {
        int orow = row0 + ((lane >> 4) << 2) + rr;
        g1b[(size_t)orow * F_HID + col]      = f2bf(acc0[rr]);
        g1b[(size_t)orow * F_HID + col + 16] = f2bf(acc1[rr]);
    }
}

// Scan: block-local exclusive scan (bucket-major view) + block totals.
// Consumers (tileFill, bucketCSR) add the bsum prefix themselves.
__global__ void k_scanLocal(const int* __restrict__ counts, int NSCAN, int NB, int NT,
                            int* __restrict__ tileOffset, int* __restrict__ bsum) {
    __shared__ int s[1024];
    int t = threadIdx.x;
    int idx = blockIdx.x * 1024 + t;
    int v = 0;
    if (idx < NSCAN) { int b = idx / NT, tt = idx - b * NT; v = counts[tt * NB + b]; }
    s[t] = v;
    __syncthreads();
    for (int off = 1; off < 1024; off <<= 1) {
        int a = (t >= off) ? s[t - off] : 0;
        __syncthreads();
        s[t] += a;
        __syncthreads();
    }
    if (idx < NSCAN) tileOffset[idx] = s[t] - v;   // local exclusive prefix
    if (t == 1023) bsum[blockIdx.x] = s[1023];     // block total
}

// LDS helper: exclusive prefix of bsum (nsb<=512) into sbp[].
__device__ __forceinline__ void bsumPrefix(const int* __restrict__ bsum, int nsb,
                                           int* sbp, int t, int nthreads) {
    // inclusive Hillis-Steele over 512 slots, then shift handled by caller use
    if (t < 512) sbp[t] = (t < nsb) ? bsum[t] : 0;
    __syncthreads();
    for (int off = 1; off < 512; off <<= 1) {
        int a = 0;
        if (t < 512 && t >= off) a = sbp[t - off];
        __syncthreads();
        if (t < 512) sbp[t] += a;
        __syncthreads();
    }
    // sbp[k] now = inclusive sum; exclusive prefix of block k = sbp[k-1] (0 for k=0)
}
__device__ __forceinline__ int sbpEx(const int* sbp, int k) {
    return k ? sbp[k - 1] : 0;
}

// Pass B: scatter packed (local8|src17) into per-(tile,bucket) contiguous runs.
__global__ __launch_bounds__(512)
void k_tileFill(const int* __restrict__ src, const int* __restrict__ dst,
                int E, int NB, int NT, const int* __restrict__ tileOffset,
                const int* __restrict__ bsum, int nsb,
                int* __restrict__ pairBuf) {
    __shared__ int lcur[HSZ];
    __shared__ int sbp[512];
    int bid = blockIdx.x;
    int xcd = bid & 7;
    int idx = bid >> 3;
    int q = NT >> 3, r = NT & 7;
    int tile = (xcd < r ? xcd * (q + 1) : r * (q + 1) + (xcd - r) * q) + idx;
    int t = threadIdx.x;
    bsumPrefix(bsum, nsb, sbp, t, 512);
    for (int i = t; i < NB; i += 512) {
        int gi = i * NT + tile;
        lcur[i] = tileOffset[gi] + sbpEx(sbp, gi >> 10);
    }
    __syncthreads();
    int base = tile * TILE;
    int lim = base + TILE; if (lim > E) lim = E;
    int n4 = (lim - base) >> 2;
    const i32x4* s4 = (const i32x4*)(src + base);
    const i32x4* d4 = (const i32x4*)(dst + base);
    for (int i = t; i < n4; i += 512) {
        i32x4 s = NTL(&s4[i]);
        i32x4 d = NTL(&d4[i]);
        #pragma unroll
        for (int k = 0; k < 4; ++k) {
            int b = d[k] >> BSH;
            int pos = atomicAdd(&lcur[b], 1);                 // LDS cursor
            pairBuf[pos] = ((d[k] & (BNODES - 1)) << 17) | s[k]; // src < 2^17
        }
    }
}

// Pass C: per-bucket CSR finish (quarter-ordered) + pass-4 g1 scaling.
__global__ __launch_bounds__(512)
void k_bucketCSR(const int* __restrict__ pairBuf, const int* __restrict__ tileOffset,
                 const int* __restrict__ bsum, int nsb,
                 int NT, int NB, int E, int n,
                 int* __restrict__ degi, int* __restrict__ cursor,
                 float* __restrict__ dinv, int* __restrict__ srcSorted,
                 uint4* __restrict__ g1q) {
    __shared__ int outb[PCAP];           // 40 KB sorted output staging
    __shared__ int cntq[BNODES * 4];     // 4 KB  (node<<2 | quarter)
    __shared__ int pref[BNODES * 4];     // 4 KB  cursors
    __shared__ int sred[BNODES];         // 1 KB
    __shared__ int sbp[512];             // 2 KB  bsum prefix
    __shared__ float sdinv[BNODES];      // 1 KB
    int b = blockIdx.x, t = threadIdx.x;
    bsumPrefix(bsum, nsb, sbp, t, 512);
    for (int i = t; i < BNODES * 4; i += 512) cntq[i] = 0;
    __syncthreads();
    int gi0 = b * NT;
    int bs = tileOffset[gi0] + sbpEx(sbp, gi0 >> 10);
    int be;
    if (b + 1 < NB) {
        int gi1 = (b + 1) * NT;
        be = tileOffset[gi1] + sbpEx(sbp, gi1 >> 10);
    } else be = E;
    int sz = be - bs;
    int th1 = n >> 2, th2 = n >> 1, th3 = (n >> 2) + (n >> 1);
    // pass 1: histogram over (node, quarter)
    for (int j = bs + t; j < be; j += 512) {
        int p = pairBuf[j];
        int s = p & 0x1FFFF;
        int q = (s >= th1) + (s >= th2) + (s >= th3);
        atomicAdd(&cntq[((p >> 17) << 2) | q], 1);
    }
    __syncthreads();
    // exclusive scan over 1024 entries (threads 0..255 own 4 each)
    int v0 = 0, v1 = 0, v2 = 0, v3 = 0, sum = 0, base = 0;
    if (t < BNODES) {
        base = t << 2;
        v0 = cntq[base]; v1 = cntq[base + 1]; v2 = cntq[base + 2]; v3 = cntq[base + 3];
        sum = v0 + v1 + v2 + v3;
        sred[t] = sum;
    }
    __syncthreads();
    for (int off = 1; off < BNODES; off <<= 1) {
        int a = (t < BNODES && t >= off) ? sred[t - off] : 0;
        __syncthreads();
        if (t < BNODES) sred[t] += a;
        __syncthreads();
    }
    if (t < BNODES) {
        int ex = sred[t] - sum;          // relative exclusive prefix
        pref[base]     = ex;
        pref[base + 1] = ex + v0;
        pref[base + 2] = ex + v0 + v1;
        pref[base + 3] = ex + v0 + v1 + v2;
        int node = (b << BSH) + t;
        if (node < n) {
            float di = rsqrtf((float)sum + 1.0f);  // +1 self-loop
            degi[node]   = sum;
            cursor[node] = bs + ex;
            dinv[node]   = di;
            sdinv[t]     = di;
        }
    }
    __syncthreads();
    // pass 2: placement into LDS (relative positions); global fallback tail
    for (int j = bs + t; j < be; j += 512) {
        int p = pairBuf[j];
        int s = p & 0x1FFFF;
        int q = (s >= th1) + (s >= th2) + (s >= th3);
        int pos = atomicAdd(&pref[((p >> 17) << 2) | q], 1);
        if (pos < PCAP) outb[pos] = s;
        else            srcSorted[bs + pos] = s;
    }
    __syncthreads();
    // pass 3: coalesced dump LDS -> global
    int lim = sz < PCAP ? sz : PCAP;
    for (int idx = t; idx < lim; idx += 512) srcSorted[bs + idx] = outb[idx];
    // pass 4: scale g1 rows (bucket-local 16KB r/w): g1u[node] *= dinv[node]
    int nodeBase = b << BSH;
    for (int i = t; i < BNODES * 4; i += 512) {
        int node = nodeBase + (i >> 2);
        if (node < n) {
            float di = sdinv[i >> 2];
            uint4 v = g1q[(size_t)node * 4 + (i & 3)];
            uint4 o;
            o.x = pack2(f2bf(di * bf2f((unsigned short)v.x)),
                        f2bf(di * bf2f((unsigned short)(v.x >> 16))));
            o.y = pack2(f2bf(di * bf2f((unsigned short)v.y)),
                        f2bf(di * bf2f((unsigned short)(v.y >> 16))));
            o.z = pack2(f2bf(di * bf2f((unsigned short)v.z)),
                        f2bf(di * bf2f((unsigned short)(v.z >> 16))));
            o.w = pack2(f2bf(di * bf2f((unsigned short)v.w)),
                        f2bf(di * bf2f((unsigned short)(v.w >> 16))));
            g1q[(size_t)node * 4 + (i & 3)] = o;
        }
    }
}

// Gather conv1 + ReLU + tiny GEMM2 fused. g1 rows PRE-SCALED.
// 8 lanes/node: two quads walk interleaved edges; sub-lane f owns feats
// 8f..8f+7 (uint4). Quads combined via shfl_xor(4). One random line/edge.
__global__ void k_gather1l2(const uint4* __restrict__ g1q, const int* __restrict__ srcSorted,
                            const int* __restrict__ cursor, const int* __restrict__ degi,
                            const float* __restrict__ dinv, const float* __restrict__ b1,
                            const float* __restrict__ W2, uint4* __restrict__ g2q, int n) {
    int t = threadIdx.x;
    int c = t & 7;                        // lane within node group
    int q = c >> 2;                       // quad 0/1
    int f = c & 3;                        // owns feats 8f..8f+7
    int node = blockIdx.x * 32 + (t >> 3);
    if (node >= n) return;
    int start = cursor[node];
    int end = start + degi[node];
    float a[8], b[8];
    #pragma unroll
    for (int k = 0; k < 8; ++k) { a[k] = 0.f; b[k] = 0.f; }
    if (q == 0) acc8(a, g1q[node * 4 + f]);   // self-loop (quad 0 only)
    int j = start + q;
    for (; j + 6 < end; j += 8) {             // 4 edges per quad per iter
        int s0 = srcSorted[j];
        int s1 = srcSorted[j + 2];
        int s2 = srcSorted[j + 4];
        int s3 = srcSorted[j + 6];
        uint4 v0 = g1q[s0 * 4 + f];
        uint4 v1 = g1q[s1 * 4 + f];
        uint4 v2 = g1q[s2 * 4 + f];
        uint4 v3 = g1q[s3 * 4 + f];
        acc8(a, v0); acc8(b, v1); acc8(a, v2); acc8(b, v3);
    }
    for (; j < end; j += 2) acc8(a, g1q[srcSorted[j] * 4 + f]);
    float af[8];
    #pragma unroll
    for (int k = 0; k < 8; ++k) {
        af[k] = a[k] + b[k];
        af[k] += __shfl_xor(af[k], 4, 64);    // combine quads
    }
    float di = dinv[node];
    float h[8];
    #pragma unroll
    for (int k = 0; k < 8; ++k) {
        float v = di * af[k] + b1[8 * f + k];
        h[k] = v > 0.f ? v : 0.f;
    }
    float p[F_OUT];
    #pragma unroll
    for (int k = 0; k < F_OUT; ++k) {
        float s = 0.f;
        #pragma unroll
        for (int f8 = 0; f8 < 8; ++f8) s += h[f8] * W2[(8 * f + f8) * F_OUT + k];
        p[k] = s;
    }
    #pragma unroll
    for (int m = 1; m < 4; m <<= 1) {
        #pragma unroll
        for (int k = 0; k < F_OUT; ++k) p[k] += __shfl_xor(p[k], m, 64);
    }
    if (c == 0) {
        uint4 qv;
        qv.x = pack2(f2bf(di * p[0]), f2bf(di * p[1]));
        qv.y = pack2(f2bf(di * p[2]), f2bf(di * p[3]));
        qv.z = pack2(f2bf(di * p[4]), f2bf(di * p[5]));
        qv.w = pack2(f2bf(di * p[6]), 0);
        g2q[node] = qv;                   // 16B bf16 row (8 slots, last = 0)
    }
}

// Gather conv2 + bias + log-softmax fused. 1 lane/node, uint4 row loads,
// i32x4 index loads, softmax fully in-thread. out store nt.
__global__ void k_gather2final(const uint4* __restrict__ g2q,
                               const int* __restrict__ srcSorted,
                               const int* __restrict__ cursor, const int* __restrict__ degi,
                               const float* __restrict__ dinv, const float* __restrict__ b2,
                               float* __restrict__ out, int n) {
    int node = blockIdx.x * 256 + threadIdx.x;
    if (node >= n) return;
    int start = cursor[node];
    int end = start + degi[node];
    float A[8], B[8];
    #pragma unroll
    for (int f = 0; f < 8; ++f) { A[f] = 0.f; B[f] = 0.f; }
    acc8(A, g2q[node]);                   // self-loop init (slot 7 = 0)
    int j = start;
    while (j < end && (j & 3)) { acc8(B, g2q[srcSorted[j]]); ++j; }  // align head
    for (; j + 4 <= end; j += 4) {
        i32x4 sA = *(const i32x4*)&srcSorted[j];
        uint4 r0 = g2q[sA[0]];
        uint4 r1 = g2q[sA[1]];
        uint4 r2 = g2q[sA[2]];
        uint4 r3 = g2q[sA[3]];
        acc8(A, r0); acc8(B, r1); acc8(A, r2); acc8(B, r3);
    }
    for (; j < end; ++j) acc8(A, g2q[srcSorted[j]]);
    float di = dinv[node];
    float v[F_OUT];
    float m = -1e30f;
    #pragma unroll
    for (int k = 0; k < F_OUT; ++k) {
        v[k] = di * (A[k] + B[k]) + b2[k];
        m = fmaxf(m, v[k]);
    }
    float ssum = 0.f;
    #pragma unroll
    for (int k = 0; k < F_OUT; ++k) ssum += __expf(v[k] - m);
    float ls = __logf(ssum) + m;
    #pragma unroll
    for (int k = 0; k < F_OUT; ++k)
        __builtin_nontemporal_store(v[k] - ls, &out[node * F_OUT + k]);
}

extern "C" void kernel_launch(void* const* d_in, const int* in_sizes, int n_in,
                              void* d_out, int out_size, void* d_ws, size_t ws_size,
                              hipStream_t stream) {
    const float* x  = (const float*)d_in[0];
    const int*   ei = (const int*)d_in[1];
    const float* W1 = (const float*)d_in[2];
    const float* b1 = (const float*)d_in[3];
    const float* W2 = (const float*)d_in[4];
    const float* b2 = (const float*)d_in[5];
    float* out = (float*)d_out;

    int n = in_sizes[0] / F_IN;            // 100000
    int E = in_sizes[1] / 2;               // 3200000
    const int* src = ei;
    const int* dst = ei + E;
    int NB = (n + BNODES - 1) >> BSH;      // 391 buckets
    int NT = (E + TILE - 1) / TILE;        // 391 tiles
    int NSCAN = NB * NT;                   // 152881
    int nsb = (NSCAN + 1023) / 1024;       // 150 scan blocks (<=512)
    int ngem = (n + 127) / 128;            // 782 gemm blocks

    // workspace layout (g1b separate from pairBuf: both live simultaneously)
    int*            degi       = (int*)d_ws;                  // [n]
    int*            cursor     = degi + n;                    // [n]
    float*          dinv       = (float*)(cursor + n);        // [n]
    int*            srcSorted  = (int*)(dinv + n);            // [E]  (16B-aligned)
    int*            pairBuf    = srcSorted + E;               // [E]
    unsigned short* g1b        = (unsigned short*)(pairBuf + E); // [n*32] bf16
    unsigned short* g2b        = g1b + (size_t)n * F_HID;     // [n*8] bf16
    int*            counts     = (int*)(g2b + (size_t)n * 8); // [NSCAN] tile-major
    int*            tileOffset = counts + NSCAN;              // [NSCAN] bucket-major (local)
    int*            bsum       = tileOffset + NSCAN;          // [nsb]

    k_histGemm<<<NT + ngem, 512, 0, stream>>>(dst, E, NB, NT, counts, x, W1, g1b, n);
    k_scanLocal<<<nsb, 1024, 0, stream>>>(counts, NSCAN, NB, NT, tileOffset, bsum);
    k_tileFill<<<NT, 512, 0, stream>>>(src, dst, E, NB, NT, tileOffset, bsum, nsb, pairBuf);
    k_bucketCSR<<<NB, 512, 0, stream>>>(pairBuf, tileOffset, bsum, nsb, NT, NB, E, n,
                                        degi, cursor, dinv, srcSorted, (uint4*)g1b);
    k_gather1l2<<<(n + 31) / 32, 256, 0, stream>>>((const uint4*)g1b, srcSorted, cursor, degi,
                                                   dinv, b1, W2, (uint4*)g2b, n);
    k_gather2final<<<(n + 255) / 256, 256, 0, stream>>>((const uint4*)g2b, srcSorted, cursor,
                                                        degi, dinv, b2, out, n);
}